// Round 8
// baseline (1891.245 us; speedup 1.0000x reference)
//
#include <hip/hip_runtime.h>
#include <math.h>

#define S_LEN 2048
#define HD    64
#define QT    16      // query rows per block (one 16-row MFMA tile)
#define NT    512     // threads per block (8 waves)
#define NW    8       // waves per block
#define NTIL  16      // 16-col score tiles per wave (16*16*8 waves = 2048 cols)
#define CAP   512     // candidate capacity per row
#define NITER 28      // bisection iters (generic-alpha fallback path only)
#define NEWT  8       // Newton iters: worst case (all-equal cluster k=512) |dtau|~2e-6 at 8

typedef short s8v __attribute__((ext_vector_type(8)));   // 8 bf16 (4 VGPRs) MFMA A/B frag
typedef float f4v __attribute__((ext_vector_type(4)));   // MFMA C/D frag

template <bool B> struct BoolT { static constexpr bool value = B; };

__device__ __forceinline__ float wave_sum(float v) {
#pragma unroll
    for (int off = 32; off >= 1; off >>= 1)
        v += __shfl_xor(v, off, 64);
    return v;
}

// ---- DPP reductions (VALU pipe, no DS traffic) ----
template <int CTRL, int RMASK>
__device__ __forceinline__ float dpp_add_step(float v) {
    int t = __builtin_amdgcn_update_dpp(0, __float_as_int(v), CTRL, RMASK, 0xf, false);
    return v + __int_as_float(t);
}

// Prefix-max within each 16-lane row; lane 15 of the row holds the row max.
__device__ __forceinline__ float dpp_row16_max(float v) {
    constexpr int NEG_INF = (int)0xff800000u;
    int t;
    t = __builtin_amdgcn_update_dpp(NEG_INF, __float_as_int(v), 0x111, 0xf, 0xf, false);
    v = fmaxf(v, __int_as_float(t));
    t = __builtin_amdgcn_update_dpp(NEG_INF, __float_as_int(v), 0x112, 0xf, 0xf, false);
    v = fmaxf(v, __int_as_float(t));
    t = __builtin_amdgcn_update_dpp(NEG_INF, __float_as_int(v), 0x114, 0xf, 0xf, false);
    v = fmaxf(v, __int_as_float(t));
    t = __builtin_amdgcn_update_dpp(NEG_INF, __float_as_int(v), 0x118, 0xf, 0xf, false);
    v = fmaxf(v, __int_as_float(t));
    return v;
}

// two RNE f32->bf16 packed: single HW instruction (S0 -> low16, S1 -> high16).
__device__ __forceinline__ unsigned f2bf2(float lo, float hi) {
    unsigned r;
    asm("v_cvt_pk_bf16_f32 %0, %1, %2" : "=v"(r) : "v"(lo), "v"(hi));
    return r;
}

__device__ __forceinline__ s8v pack_bf8(const float4& x, const float4& y, float sc) {
    union { s8v s; unsigned u[4]; } f;
    f.u[0] = f2bf2(x.x * sc, x.y * sc);
    f.u[1] = f2bf2(x.z * sc, x.w * sc);
    f.u[2] = f2bf2(y.x * sc, y.y * sc);
    f.u[3] = f2bf2(y.z * sc, y.w * sc);
    return f.s;
}

template <bool INV2>
__device__ __forceinline__ float pfun_t(float t, float inv) {
    float u = fmaxf(t, 0.0f);
    return INV2 ? u * u : powf(u, inv);
}

// ---- alpha=1.5 fast path: Newton on f(tau)=sum max(c-tau,0)^2 - 1 ----
// Monotone from tau0=max-1 (convex f); after NEWT iters |sum-1| <= ~1e-4 ->
// isum == 1 (normalization pass dropped; error << output tolerance).
template <int NR>
__device__ __forceinline__ float newton_reg(const float* cvrow, int nc, int lane,
                                            float tau0) {
    float c[NR];
#pragma unroll
    for (int j = 0; j < NR; ++j) {
        int i = lane + 64 * j;
        c[j] = (i < nc) ? cvrow[i] : -3.0e38f;
    }
    float tau = tau0;
#pragma unroll
    for (int it = 0; it < NEWT; ++it) {
        float s1 = 0.0f, s2 = 0.0f;
#pragma unroll
        for (int j = 0; j < NR; ++j) {
            float u = fmaxf(c[j] - tau, 0.0f);
            s1 += u;
            s2 = fmaf(u, u, s2);
        }
        s1 = dpp_add_step<0x111, 0xf>(s1);  s2 = dpp_add_step<0x111, 0xf>(s2);
        s1 = dpp_add_step<0x112, 0xf>(s1);  s2 = dpp_add_step<0x112, 0xf>(s2);
        s1 = dpp_add_step<0x114, 0xf>(s1);  s2 = dpp_add_step<0x114, 0xf>(s2);
        s1 = dpp_add_step<0x118, 0xf>(s1);  s2 = dpp_add_step<0x118, 0xf>(s2);
        s1 = dpp_add_step<0x142, 0xa>(s1);  s2 = dpp_add_step<0x142, 0xa>(s2);
        s1 = dpp_add_step<0x143, 0xc>(s1);  s2 = dpp_add_step<0x143, 0xc>(s2);
        const float S1 = __int_as_float(__builtin_amdgcn_readlane(__float_as_int(s1), 63));
        const float S2 = __int_as_float(__builtin_amdgcn_readlane(__float_as_int(s2), 63));
        tau += (S2 - 1.0f) * 0.5f * __builtin_amdgcn_rcpf(fmaxf(S1, 1e-30f));
    }
    return tau;
}

// Register-resident bisection (generic-alpha fallback; not hit for alpha=1.5).
template <int NR, bool INV2>
__device__ __forceinline__ void bisect_reg(const float* cvrow, int nc, int lane,
                                           float tau_lo0, float tau_hi, float inv,
                                           float& tau_out, float& isum_out) {
    float c[NR];
#pragma unroll
    for (int j = 0; j < NR; ++j) {
        int i = lane + 64 * j;
        c[j] = (i < nc) ? cvrow[i] : -3.0e38f;
    }
    float tau = tau_lo0;
    float s0 = 0.0f;
#pragma unroll
    for (int j = 0; j < NR; ++j) s0 += pfun_t<INV2>(c[j] - tau, inv);
    const float f_lo = wave_sum(s0) - 1.0f;
    float dm = tau_hi - tau_lo0;
    for (int it = 0; it < NITER; ++it) {
        dm *= 0.5f;
        float tm = tau + dm;
        float s = 0.0f;
#pragma unroll
        for (int j = 0; j < NR; ++j) s += pfun_t<INV2>(c[j] - tm, inv);
        float fm = wave_sum(s) - 1.0f;
        if (fm * f_lo >= 0.0f) tau = tm;
    }
    float s = 0.0f;
#pragma unroll
    for (int j = 0; j < NR; ++j) s += pfun_t<INV2>(c[j] - tau, inv);
    float ssum = wave_sum(s);
    tau_out = tau;
    isum_out = 1.0f / ssum;
}

// ---- prepass: K and V f32 -> bf16 in MFMA-fragment order (unchanged) ----
__global__ __launch_bounds__(256)
void pack_kv(const float* __restrict__ Kp, const float* __restrict__ Vp,
             s8v* __restrict__ Kb, s8v* __restrict__ Vb, int nK) {
    int idx = blockIdx.x * 256 + threadIdx.x;
    if (idx < nK) {
        const int lane = idx & 63, frag = (idx >> 6) & 1, tile = (idx >> 7) & 127, bh = idx >> 14;
        const int l16 = lane & 15, quad = lane >> 4;
        const float* src = Kp + ((size_t)(bh * S_LEN + tile * 16 + l16)) * HD + frag * 32 + quad * 8;
        float4 a = *(const float4*)src;
        float4 b = *(const float4*)(src + 4);
        Kb[idx] = pack_bf8(a, b, 1.0f);
    } else {
        int v = idx - nK;
        const int lane = v & 63, dt = (v >> 6) & 3, kt32 = (v >> 8) & 63, bh = v >> 14;
        const int l16 = lane & 15, quad = lane >> 4;
        const int base_row = (kt32 >> 2) * 128 + (kt32 & 3) * 4 + quad;  // j stride = 16 rows
        const float* src = Vp + ((size_t)(bh * S_LEN + base_row)) * HD + dt * 16 + l16;
        float w[8];
#pragma unroll
        for (int j = 0; j < 8; ++j) w[j] = src[(size_t)j * 16 * HD];
        float4 a = {w[0], w[1], w[2], w[3]};
        float4 b = {w[4], w[5], w[6], w[7]};
        Vb[v] = pack_bf8(a, b, 1.0f);
    }
}

// bf16 MFMA QK^T. C/D layout (HW-verified m89): col=lane&15, row=(lane>>4)*4+reg.
template <bool PREK, bool DPV>
__global__ __launch_bounds__(NT, 4)
void entmax_attn(const float* __restrict__ Qp, const float* __restrict__ Kp,
                 const float* __restrict__ Vp, const float* __restrict__ alphap,
                 float* __restrict__ outp, float* __restrict__ pattn,
                 const s8v* __restrict__ Kbf, const s8v* __restrict__ Vbf) {
    // shared region, time-multiplexed:
    //  phases 3-4: candv[QT][CAP] f32 (32KB) (+candi if !DPV)
    //  phase 6 (DPV): pw bf16 staging 8 waves x 4KB (32KB, two 128-col passes);
    //                 each wave's 4KB then reused for its f32 PV partial [16][64]
    constexpr int SM_BIG = DPV ? (NW * 4096 > QT * CAP * 4 ? NW * 4096 : QT * CAP * 4)
                               : (QT * CAP * 4 + QT * CAP * 2);
    __shared__ __align__(16) char smem[SM_BIG];
    float          (*candv)[CAP] = (float(*)[CAP])smem;
    unsigned short (*candi)[CAP] = (unsigned short(*)[CAP])(smem + QT * CAP * 4);

    __shared__ int   ncnt[QT];
    __shared__ float rmaxw[QT][NW];
    __shared__ float rmxf[QT];
    __shared__ float taus[QT];
    __shared__ float isums[QT];
    __shared__ float redw[NW];

    const int tid   = threadIdx.x;
    const int wv    = tid >> 6;
    const int lane  = tid & 63;
    const int quad  = lane >> 4;
    const int l16   = lane & 15;
    const int bh    = blockIdx.y;
    const int q0    = blockIdx.x * QT;
    const int wcol0 = wv * (NTIL * 16);    // 256 score cols per wave

    const float alpha = alphap[0];
    const float am1   = alpha - 1.0f;
    const float inv   = 1.0f / am1;
    const bool  inv2  = (inv == 2.0f);
    const float xscale = (1.0f / sqrtf((float)HD)) * am1;  // folded into Q before bf16
    const float gp_d   = powf(1.0f / (float)S_LEN, am1);

    if (tid < QT) ncnt[tid] = 0;

    const float* vbase = Vp + (size_t)bh * S_LEN * HD;

    // ---- Phase 1: Xa = (Q*xscale) @ K^T via MFMA, accumulators in regs ----
    s8v qa0, qa1;
    {
        const float* qp = Qp + ((size_t)bh * S_LEN + q0 + l16) * HD + quad * 8;
        float4 x0 = *(const float4*)qp;
        float4 x1 = *(const float4*)(qp + 4);
        float4 y0 = *(const float4*)(qp + 32);
        float4 y1 = *(const float4*)(qp + 36);
        qa0 = pack_bf8(x0, x1, xscale);   // k = 0..31 slice
        qa1 = pack_bf8(y0, y1, xscale);   // k = 32..63 slice
    }

    f4v xa[NTIL];
    if constexpr (PREK) {
        const s8v* kf = Kbf + ((size_t)bh * (S_LEN / 16) + (wcol0 >> 4)) * 2 * 64 + lane;
        __builtin_amdgcn_s_setprio(1);
#pragma unroll
        for (int t = 0; t < NTIL; ++t) {
            s8v kb0 = kf[(2 * t    ) * 64];
            s8v kb1 = kf[(2 * t + 1) * 64];
            f4v acc = {0.0f, 0.0f, 0.0f, 0.0f};
            acc = __builtin_amdgcn_mfma_f32_16x16x32_bf16(qa0, kb0, acc, 0, 0, 0);
            acc = __builtin_amdgcn_mfma_f32_16x16x32_bf16(qa1, kb1, acc, 0, 0, 0);
            xa[t] = acc;
        }
        __builtin_amdgcn_s_setprio(0);
    } else {
        const float* kbase = Kp + (size_t)bh * S_LEN * HD;
#pragma unroll
        for (int t = 0; t < NTIL; ++t) {
            const float* kp = kbase + ((size_t)(wcol0 + t * 16 + l16)) * HD + quad * 8;
            float4 k0 = *(const float4*)kp;
            float4 k1 = *(const float4*)(kp + 4);
            s8v kb0 = pack_bf8(k0, k1, 1.0f);
            f4v acc = {0.0f, 0.0f, 0.0f, 0.0f};
            acc = __builtin_amdgcn_mfma_f32_16x16x32_bf16(qa0, kb0, acc, 0, 0, 0);
            float4 k2 = *(const float4*)(kp + 32);
            float4 k3 = *(const float4*)(kp + 36);
            s8v kb1 = pack_bf8(k2, k3, 1.0f);
            acc = __builtin_amdgcn_mfma_f32_16x16x32_bf16(qa1, kb1, acc, 0, 0, 0);
            xa[t] = acc;
        }
    }

    // ---- Phase 2: exact row maxes (row = quad*4+g within the Q tile) ----
#pragma unroll
    for (int g = 0; g < 4; ++g) {
        float pm = xa[0][g];
#pragma unroll
        for (int t = 1; t < NTIL; ++t) pm = fmaxf(pm, xa[t][g]);
        pm = dpp_row16_max(pm);
        if (l16 == 15) rmaxw[quad * 4 + g][wv] = pm;
    }
    __syncthreads();
    if (tid < QT) {
        float m = rmaxw[tid][0];
#pragma unroll
        for (int w = 1; w < NW; ++w) m = fmaxf(m, rmaxw[tid][w]);
        rmxf[tid] = m;
    }
    __syncthreads();

    // ---- Phase 3: candidate compaction (two 8-tile halves; ballots kept
    // in SGPRs across count+scatter; SALU quad totals; readlane broadcast) ----
#pragma unroll
    for (int h = 0; h < 2; ++h) {
#pragma unroll
        for (int g = 0; g < 4; ++g) {
            const int   row = quad * 4 + g;
            const float thr = rmxf[row] - 1.0f;
            unsigned long long bm[8];
            unsigned tq0 = 0, tq1 = 0, tq2 = 0, tq3 = 0;   // uniform -> SALU
#pragma unroll
            for (int t = 0; t < 8; ++t) {
                bm[t] = __ballot(xa[h * 8 + t][g] > thr);
                tq0 += (unsigned)__popcll(bm[t] & 0x000000000000FFFFull);
                tq1 += (unsigned)__popcll(bm[t] & 0x00000000FFFF0000ull);
                tq2 += (unsigned)__popcll(bm[t] & 0x0000FFFF00000000ull);
                tq3 += (unsigned)__popcll(bm[t] >> 48);
            }
            const int total = (quad & 2) ? ((quad & 1) ? (int)tq3 : (int)tq2)
                                         : ((quad & 1) ? (int)tq1 : (int)tq0);
            int base = 0;
            if (l16 == 0 && total) base = atomicAdd(&ncnt[row], total);
            {   // broadcast lane {0,16,32,48} -> own quad, register-only
                const int b0 = __builtin_amdgcn_readlane(base, 0);
                const int b1 = __builtin_amdgcn_readlane(base, 16);
                const int b2 = __builtin_amdgcn_readlane(base, 32);
                const int b3 = __builtin_amdgcn_readlane(base, 48);
                base = (quad & 2) ? ((quad & 1) ? b3 : b2)
                                  : ((quad & 1) ? b1 : b0);
            }
#pragma unroll
            for (int t = 0; t < 8; ++t) {
                const float v = xa[h * 8 + t][g];
                const bool pred = (v > thr);
                unsigned gm16 = (unsigned)((bm[t] >> (quad * 16)) & 0xFFFFull);
                if (pred) {
                    int pos = base + __popc(gm16 & ((1u << l16) - 1u));
                    if (pos < CAP) {
                        candv[row][pos] = v;
                        if constexpr (!DPV)
                            candi[row][pos] = (unsigned short)(wcol0 + (h * 8 + t) * 16 + l16);
                    }
                }
                base += __popc(gm16);
            }
        }
    }
    __syncthreads();

    // ---- Tail phases, specialized on INV2 (block-uniform branch) ----
    auto tail = [&](auto inv2c) {
        constexpr bool INV2 = decltype(inv2c)::value;

        // Phase 4: per-wave tau solve; wave w owns rows w and w+8 (QT == 2*NW)
#pragma unroll 1
        for (int rr = 0; rr < 2; ++rr) {
            const int row = wv + rr * NW;
            const int nc = ncnt[row];
            if (nc <= CAP) {
                if constexpr (!DPV) {   // sparse phase 6 needs padded 8-groups
                    const int ncp = (nc + 7) & ~7;
                    for (int i = nc + lane; i < ncp; i += 64) {
                        candv[row][i] = -3.0e38f;
                        candi[row][i] = 0;
                    }
                }
                const float mx  = rmxf[row];
                const float tl0 = mx - 1.0f;
                const float th  = mx - gp_d;
                float tau, isum;
                if constexpr (INV2) {
                    if (nc <= 256) tau = newton_reg<4>(&candv[row][0], nc, lane, tl0);
                    else           tau = newton_reg<8>(&candv[row][0], nc, lane, tl0);
                    isum = 1.0f;   // converged: |sum(p)-1| <= ~1e-4
                } else {
                    if (nc <= 256) bisect_reg<4, INV2>(&candv[row][0], nc, lane, tl0, th, inv, tau, isum);
                    else           bisect_reg<8, INV2>(&candv[row][0], nc, lane, tl0, th, inv, tau, isum);
                }
                if (lane == 0) { taus[row] = tau; isums[row] = isum; }
            }
        }

        // Phase 4b: block-wide fallback for overflow rows (nc > CAP; rare)
#pragma unroll 1
        for (int r = 0; r < QT; ++r) {
            if (ncnt[r] > CAP) {   // uniform condition -> barriers are safe
                const float mx = rmxf[r];
                const int g = r & 3;
                const bool mine = (quad == (r >> 2));
                float tau = mx - 1.0f;
                float s0 = 0.0f;
                if (mine) {
#pragma unroll
                    for (int t = 0; t < NTIL; ++t) s0 += pfun_t<INV2>(xa[t][g] - tau, inv);
                }
                s0 = wave_sum(s0);
                if (lane == 0) redw[wv] = s0;
                __syncthreads();
                float f_lo = -1.0f;
                for (int w = 0; w < NW; ++w) f_lo += redw[w];
                __syncthreads();
                float dm = (mx - gp_d) - tau;
                for (int it = 0; it < NITER; ++it) {
                    dm *= 0.5f;
                    float tm = tau + dm;
                    float s = 0.0f;
                    if (mine) {
#pragma unroll
                        for (int t = 0; t < NTIL; ++t) s += pfun_t<INV2>(xa[t][g] - tm, inv);
                    }
                    s = wave_sum(s);
                    if (lane == 0) redw[wv] = s;
                    __syncthreads();
                    float fm = -1.0f;
                    for (int w = 0; w < NW; ++w) fm += redw[w];
                    __syncthreads();
                    if (fm * f_lo >= 0.0f) tau = tm;
                }
                float s = 0.0f;
                if (mine) {
#pragma unroll
                    for (int t = 0; t < NTIL; ++t) s += pfun_t<INV2>(xa[t][g] - tau, inv);
                }
                s = wave_sum(s);
                if (lane == 0) redw[wv] = s;
                __syncthreads();
                float ssum = 0.0f;
                for (int w = 0; w < NW; ++w) ssum += redw[w];
                __syncthreads();
                if (tid == 0) { taus[r] = tau; isums[r] = 1.0f / ssum; }
            }
        }
        __syncthreads();   // taus/isums visible; candv reads complete (smem reuse OK)

        if constexpr (DPV) {
            // ---- Phase 5+6 (dense PV): two 128-col passes. Per pass: write
            // p_attn (normal cached stores: L2 merges the 64B quad-chunks into
            // full lines; nt stores caused 2x write amplification via partial-
            // line RMW - R7 counters), stage bf16 p (permuted k-order) into
            // the wave's 4KB, read A-frags, MFMA vs prepacked V. oacc accums.
            unsigned short* pwf = (unsigned short*)smem + wv * 2048;  // 4KB/wave
            const size_t prow_base = ((size_t)bh * S_LEN + q0) * S_LEN;
            f4v oacc[4];
#pragma unroll
            for (int dt = 0; dt < 4; ++dt) oacc[dt] = (f4v){0.0f, 0.0f, 0.0f, 0.0f};
#pragma unroll 1
            for (int h = 0; h < 2; ++h) {
#pragma unroll
                for (int g = 0; g < 4; ++g) {
                    const int row = quad * 4 + g;
                    const float tau  = taus[row];
                    const float isum = isums[row];
                    float* prow = pattn + prow_base + (size_t)row * S_LEN + wcol0 + h * 128 + l16;
                    union { s8v s; unsigned u[4]; } pk;
                    float pprev = 0.0f;
#pragma unroll
                    for (int t = 0; t < 8; ++t) {
                        float p2 = pfun_t<INV2>(xa[h * 8 + t][g] - tau, inv);
                        prow[t * 16] = p2 * isum;             // normalized p_attn
                        if (t & 1) pk.u[t >> 1] = f2bf2(pprev, p2);
                        else       pprev = p2;
                    }
                    const int c = (l16 ^ row) & 15;               // XOR chunk swizzle
                    *(s8v*)&pwf[row * 128 + c * 8] = pk.s;        // one b128 store
                }
                // A-frags (wave-local; DS in-order): row = l16
                s8v afrag[4];
#pragma unroll
                for (int kt = 0; kt < 4; ++kt) {
                    const int c = ((kt * 4 + quad) ^ l16) & 15;
                    afrag[kt] = *(const s8v*)&pwf[l16 * 128 + c * 8];
                }
                const s8v* vf = Vbf + ((size_t)bh * (S_LEN / 32) + wv * 8 + h * 4) * 4 * 64 + lane;
                __builtin_amdgcn_s_setprio(1);
#pragma unroll
                for (int kt = 0; kt < 4; ++kt) {
#pragma unroll
                    for (int dt = 0; dt < 4; ++dt) {
                        s8v b = vf[(kt * 4 + dt) * 64];
                        oacc[dt] = __builtin_amdgcn_mfma_f32_16x16x32_bf16(afrag[kt], b, oacc[dt], 0, 0, 0);
                    }
                }
                __builtin_amdgcn_s_setprio(0);
            }
            // Wave-private partial store ALIASED onto this wave's pw region
            // (DS in-order per wave; no other wave touches this 4KB).
            // Layout [16 rows][64 d] f32 with writer-quad XOR on d.
            float* pr = (float*)pwf;
#pragma unroll
            for (int dt = 0; dt < 4; ++dt) {
#pragma unroll
                for (int g = 0; g < 4; ++g) {
                    pr[(quad * 4 + g) * 64 + ((dt * 16 + l16) ^ (quad << 4))] = oacc[dt][g];
                }
            }
            __syncthreads();   // single epilogue barrier: all partials visible
            // reduce 8 wave-partials: thread (wv,lane) owns rows wv*2, wv*2+1 (d=lane);
            // element (r,d) of wave w lives at w*1024 + r*64 + (d ^ ((r>>2)<<4))
#pragma unroll
            for (int rr = 0; rr < 2; ++rr) {
                const int row = wv * 2 + rr;
                const int rd = lane ^ ((row >> 2) << 4);
                float s = 0.0f;
#pragma unroll
                for (int w = 0; w < NW; ++w) s += ((float*)smem)[w * 1024 + row * 64 + rd];
                outp[((size_t)bh * S_LEN + q0 + row) * HD + lane] = s * isums[row];
            }
        } else {
            // ---- Phase 5: write normalized p_attn ----
            const size_t prow_base = ((size_t)bh * S_LEN + q0) * S_LEN;
#pragma unroll
            for (int g = 0; g < 4; ++g) {
                const int row = quad * 4 + g;
                const float tau  = taus[row];
                const float isum = isums[row];
                float* prow = pattn + prow_base + (size_t)row * S_LEN + wcol0 + l16;
#pragma unroll
                for (int t = 0; t < NTIL; ++t) {
                    prow[t * 16] = pfun_t<INV2>(xa[t][g] - tau, inv) * isum;
                }
            }
            __threadfence_block();
            __syncthreads();

            // ---- Phase 6: out = p @ V, sparse over candidates (lane == d);
            // wave w handles rows w and w+8 ----
#pragma unroll 1
            for (int rr = 0; rr < 2; ++rr) {
                const int row  = wv + rr * NW;
                const int qrow = q0 + row;
                const int nc   = ncnt[row];
                const float tau  = taus[row];
                const float isum = isums[row];
                float oacc = 0.0f;
                if (nc <= CAP) {
                    const int ncp = (nc + 7) & ~7;
                    for (int i = lane; i < ncp; i += 64)  // candv := unnormalized p
                        candv[row][i] = pfun_t<INV2>(candv[row][i] - tau, inv);
                    float oacc1 = 0.0f;
                    for (int i = 0; i < ncp; i += 8) {
#pragma unroll
                        for (int u = 0; u < 8; u += 2) {
                            oacc  = fmaf(candv[row][i + u],
                                         vbase[(size_t)candi[row][i + u] * HD + lane], oacc);
                            oacc1 = fmaf(candv[row][i + u + 1],
                                         vbase[(size_t)candi[row][i + u + 1] * HD + lane], oacc1);
                        }
                    }
                    oacc = (oacc + oacc1) * isum;
                } else {
                    const float* prow = pattn + ((size_t)bh * S_LEN + qrow) * S_LEN;
                    for (int k = 0; k < S_LEN; ++k)
                        oacc = fmaf(prow[k], vbase[(size_t)k * HD + lane], oacc);
                }
                outp[((size_t)bh * S_LEN + qrow) * HD + lane] = oacc;
            }
        }
    };

    if (inv2) tail(BoolT<true>{});   // alpha == 1.5 fast path (u*u)
    else      tail(BoolT<false>{});  // generic alpha (powf)
}

extern "C" void kernel_launch(void* const* d_in, const int* in_sizes, int n_in,
                              void* d_out, int out_size, void* d_ws, size_t ws_size,
                              hipStream_t stream) {
    const float* Q = (const float*)d_in[0];
    const float* K = (const float*)d_in[1];
    const float* V = (const float*)d_in[2];
    const float* A = (const float*)d_in[3];
    float* out = (float*)d_out;
    const int BH = in_sizes[0] / (S_LEN * HD);          // 64
    float* p = out + (size_t)BH * S_LEN * HD;           // p_attn follows out
    dim3 grid(S_LEN / QT, BH);

    const size_t kb_bytes = (size_t)BH * S_LEN * HD * sizeof(short);  // 16.8 MB
    const int nK = BH * (S_LEN / 16) * 2 * 64;          // K 16B frag chunks
    const int nV = BH * (S_LEN / 32) * 4 * 64;          // V 16B frag chunks

    if (d_ws != nullptr && ws_size >= 2 * kb_bytes) {
        s8v* Kb = (s8v*)d_ws;
        s8v* Vb = (s8v*)((char*)d_ws + kb_bytes);
        pack_kv<<<dim3((nK + nV) / 256), 256, 0, stream>>>(K, V, Kb, Vb, nK);
        entmax_attn<true, true><<<grid, NT, 0, stream>>>(Q, K, V, A, out, p, Kb, Vb);
    } else if (d_ws != nullptr && ws_size >= kb_bytes) {
        s8v* Kb = (s8v*)d_ws;
        pack_kv<<<dim3(nK / 256), 256, 0, stream>>>(K, V, Kb, nullptr, nK);
        entmax_attn<true, false><<<grid, NT, 0, stream>>>(Q, K, V, A, out, p, Kb, nullptr);
    } else {
        entmax_attn<false, false><<<grid, NT, 0, stream>>>(Q, K, V, A, out, p, nullptr, nullptr);
    }
}

// Round 9
// 1793.898 us; speedup vs baseline: 1.0543x; 1.0543x over previous
//
#include <hip/hip_runtime.h>
#include <math.h>

#define S_LEN 2048
#define HD    64
#define QT    16      // query rows per block (one 16-row MFMA tile)
#define NT    1024    // threads per block
#define NW    16      // waves per block
#define NTIL  8       // 16-col score tiles per wave (8*16*16 waves = 2048 cols)
#define CAP   512     // candidate capacity per row
#define NITER 28      // bisection iters (generic-alpha fallback path only)
#define NEWT  8       // Newton iters: worst case (all-equal cluster k=512) |dtau|~2e-6 at 8

typedef short s8v __attribute__((ext_vector_type(8)));   // 8 bf16 (4 VGPRs) MFMA A/B frag
typedef float f4v __attribute__((ext_vector_type(4)));   // MFMA C/D frag

template <bool B> struct BoolT { static constexpr bool value = B; };

__device__ __forceinline__ float wave_sum(float v) {
#pragma unroll
    for (int off = 32; off >= 1; off >>= 1)
        v += __shfl_xor(v, off, 64);
    return v;
}

// ---- DPP reductions (VALU pipe, no DS traffic) ----
template <int CTRL, int RMASK>
__device__ __forceinline__ float dpp_add_step(float v) {
    int t = __builtin_amdgcn_update_dpp(0, __float_as_int(v), CTRL, RMASK, 0xf, false);
    return v + __int_as_float(t);
}

// Prefix-max within each 16-lane row; lane 15 of the row holds the row max.
__device__ __forceinline__ float dpp_row16_max(float v) {
    constexpr int NEG_INF = (int)0xff800000u;
    int t;
    t = __builtin_amdgcn_update_dpp(NEG_INF, __float_as_int(v), 0x111, 0xf, 0xf, false);
    v = fmaxf(v, __int_as_float(t));
    t = __builtin_amdgcn_update_dpp(NEG_INF, __float_as_int(v), 0x112, 0xf, 0xf, false);
    v = fmaxf(v, __int_as_float(t));
    t = __builtin_amdgcn_update_dpp(NEG_INF, __float_as_int(v), 0x114, 0xf, 0xf, false);
    v = fmaxf(v, __int_as_float(t));
    t = __builtin_amdgcn_update_dpp(NEG_INF, __float_as_int(v), 0x118, 0xf, 0xf, false);
    v = fmaxf(v, __int_as_float(t));
    return v;
}

// two RNE f32->bf16 packed: single HW instruction (S0 -> low16, S1 -> high16).
__device__ __forceinline__ unsigned f2bf2(float lo, float hi) {
    unsigned r;
    asm("v_cvt_pk_bf16_f32 %0, %1, %2" : "=v"(r) : "v"(lo), "v"(hi));
    return r;
}

__device__ __forceinline__ s8v pack_bf8(const float4& x, const float4& y, float sc) {
    union { s8v s; unsigned u[4]; } f;
    f.u[0] = f2bf2(x.x * sc, x.y * sc);
    f.u[1] = f2bf2(x.z * sc, x.w * sc);
    f.u[2] = f2bf2(y.x * sc, y.y * sc);
    f.u[3] = f2bf2(y.z * sc, y.w * sc);
    return f.s;
}

template <bool INV2>
__device__ __forceinline__ float pfun_t(float t, float inv) {
    float u = fmaxf(t, 0.0f);
    return INV2 ? u * u : powf(u, inv);
}

// ---- alpha=1.5 fast path: Newton on f(tau)=sum max(c-tau,0)^2 - 1 ----
// Monotone from tau0=max-1 (convex f); after NEWT iters |sum-1| <= ~1e-4 ->
// isum == 1 (normalization pass dropped; error << output tolerance).
template <int NR>
__device__ __forceinline__ float newton_reg(const float* cvrow, int nc, int lane,
                                            float tau0) {
    float c[NR];
#pragma unroll
    for (int j = 0; j < NR; ++j) {
        int i = lane + 64 * j;
        c[j] = (i < nc) ? cvrow[i] : -3.0e38f;
    }
    float tau = tau0;
#pragma unroll
    for (int it = 0; it < NEWT; ++it) {
        float s1 = 0.0f, s2 = 0.0f;
#pragma unroll
        for (int j = 0; j < NR; ++j) {
            float u = fmaxf(c[j] - tau, 0.0f);
            s1 += u;
            s2 = fmaf(u, u, s2);
        }
        s1 = dpp_add_step<0x111, 0xf>(s1);  s2 = dpp_add_step<0x111, 0xf>(s2);
        s1 = dpp_add_step<0x112, 0xf>(s1);  s2 = dpp_add_step<0x112, 0xf>(s2);
        s1 = dpp_add_step<0x114, 0xf>(s1);  s2 = dpp_add_step<0x114, 0xf>(s2);
        s1 = dpp_add_step<0x118, 0xf>(s1);  s2 = dpp_add_step<0x118, 0xf>(s2);
        s1 = dpp_add_step<0x142, 0xa>(s1);  s2 = dpp_add_step<0x142, 0xa>(s2);
        s1 = dpp_add_step<0x143, 0xc>(s1);  s2 = dpp_add_step<0x143, 0xc>(s2);
        const float S1 = __int_as_float(__builtin_amdgcn_readlane(__float_as_int(s1), 63));
        const float S2 = __int_as_float(__builtin_amdgcn_readlane(__float_as_int(s2), 63));
        tau += (S2 - 1.0f) * 0.5f * __builtin_amdgcn_rcpf(fmaxf(S1, 1e-30f));
    }
    return tau;
}

// Register-resident bisection (generic-alpha fallback; not hit for alpha=1.5).
template <int NR, bool INV2>
__device__ __forceinline__ void bisect_reg(const float* cvrow, int nc, int lane,
                                           float tau_lo0, float tau_hi, float inv,
                                           float& tau_out, float& isum_out) {
    float c[NR];
#pragma unroll
    for (int j = 0; j < NR; ++j) {
        int i = lane + 64 * j;
        c[j] = (i < nc) ? cvrow[i] : -3.0e38f;
    }
    float tau = tau_lo0;
    float s0 = 0.0f;
#pragma unroll
    for (int j = 0; j < NR; ++j) s0 += pfun_t<INV2>(c[j] - tau, inv);
    const float f_lo = wave_sum(s0) - 1.0f;
    float dm = tau_hi - tau_lo0;
    for (int it = 0; it < NITER; ++it) {
        dm *= 0.5f;
        float tm = tau + dm;
        float s = 0.0f;
#pragma unroll
        for (int j = 0; j < NR; ++j) s += pfun_t<INV2>(c[j] - tm, inv);
        float fm = wave_sum(s) - 1.0f;
        if (fm * f_lo >= 0.0f) tau = tm;
    }
    float s = 0.0f;
#pragma unroll
    for (int j = 0; j < NR; ++j) s += pfun_t<INV2>(c[j] - tau, inv);
    float ssum = wave_sum(s);
    tau_out = tau;
    isum_out = 1.0f / ssum;
}

// ---- prepass: K and V f32 -> bf16 in MFMA-fragment order ----
// K chunk idx = ((bh*128 + tile)*2 + frag)*64 + lane:
//   K[tile*16 + l16][frag*32 + quad*8 + j]
// V chunk idx = ((bh*64 + kt32)*4 + dt)*64 + lane, with the PERMUTED k-order
// (within each 128-col block, position p holds orig col (p&7)*16 + (p>>3)):
//   p = kt32*32 + quad*8 + j  ->  orig k = (kt32>>2)*128 + j*16 + (kt32&3)*4 + quad
//   stored value = V[orig k][dt*16 + l16]
__global__ __launch_bounds__(256)
void pack_kv(const float* __restrict__ Kp, const float* __restrict__ Vp,
             s8v* __restrict__ Kb, s8v* __restrict__ Vb, int nK) {
    int idx = blockIdx.x * 256 + threadIdx.x;
    if (idx < nK) {
        const int lane = idx & 63, frag = (idx >> 6) & 1, tile = (idx >> 7) & 127, bh = idx >> 14;
        const int l16 = lane & 15, quad = lane >> 4;
        const float* src = Kp + ((size_t)(bh * S_LEN + tile * 16 + l16)) * HD + frag * 32 + quad * 8;
        float4 a = *(const float4*)src;
        float4 b = *(const float4*)(src + 4);
        Kb[idx] = pack_bf8(a, b, 1.0f);
    } else {
        int v = idx - nK;
        const int lane = v & 63, dt = (v >> 6) & 3, kt32 = (v >> 8) & 63, bh = v >> 14;
        const int l16 = lane & 15, quad = lane >> 4;
        const int base_row = (kt32 >> 2) * 128 + (kt32 & 3) * 4 + quad;  // j stride = 16 rows
        const float* src = Vp + ((size_t)(bh * S_LEN + base_row)) * HD + dt * 16 + l16;
        float w[8];
#pragma unroll
        for (int j = 0; j < 8; ++j) w[j] = src[(size_t)j * 16 * HD];
        float4 a = {w[0], w[1], w[2], w[3]};
        float4 b = {w[4], w[5], w[6], w[7]};
        Vb[v] = pack_bf8(a, b, 1.0f);
    }
}

// bf16 MFMA QK^T. C/D layout (HW-verified m89): col=lane&15, row=(lane>>4)*4+reg.
// A/B frag: lane holds [m|n = lane&15][k = (lane>>4)*8 + j], j=0..7.
template <bool PREK, bool DPV>
__global__ __launch_bounds__(NT)
void entmax_attn(const float* __restrict__ Qp, const float* __restrict__ Kp,
                 const float* __restrict__ Vp, const float* __restrict__ alphap,
                 float* __restrict__ outp, float* __restrict__ pattn,
                 const s8v* __restrict__ Kbf, const s8v* __restrict__ Vbf) {
    // big shared region, time-multiplexed:
    //  phases 3-4: candv[QT][CAP] f32 (32KB) (+candi[QT][CAP] u16 if !DPV)
    //  phase 6 (DPV): pw bf16 staging 16 waves x 4KB (64KB); each wave's 4KB
    //                 is then reused (wave-private, DS in-order) for its f32
    //                 PV partial [16][64] -> only ONE barrier in the epilogue
    constexpr int SM_BIG = DPV ? (NW * 4096)
                               : (QT * CAP * 4 + QT * CAP * 2);
    __shared__ __align__(16) char smem[SM_BIG];
    float          (*candv)[CAP] = (float(*)[CAP])smem;
    unsigned short (*candi)[CAP] = (unsigned short(*)[CAP])(smem + QT * CAP * 4);

    __shared__ int   ncnt[QT];
    __shared__ float rmaxw[QT][NW];
    __shared__ float rmxf[QT];
    __shared__ float taus[QT];
    __shared__ float isums[QT];
    __shared__ float redw[NW];

    const int tid   = threadIdx.x;
    const int wv    = tid >> 6;
    const int lane  = tid & 63;
    const int quad  = lane >> 4;
    const int l16   = lane & 15;
    const int bh    = blockIdx.y;
    const int q0    = blockIdx.x * QT;
    const int wcol0 = wv * (NTIL * 16);    // 128 score cols per wave

    const float alpha = alphap[0];
    const float am1   = alpha - 1.0f;
    const float inv   = 1.0f / am1;
    const bool  inv2  = (inv == 2.0f);
    const float xscale = (1.0f / sqrtf((float)HD)) * am1;  // folded into Q before bf16
    const float gp_d   = powf(1.0f / (float)S_LEN, am1);

    if (tid < QT) ncnt[tid] = 0;

    const float* vbase = Vp + (size_t)bh * S_LEN * HD;

    // ---- Phase 1: Xa = (Q*xscale) @ K^T via MFMA, accumulators in regs ----
    s8v qa0, qa1;
    {
        const float* qp = Qp + ((size_t)bh * S_LEN + q0 + l16) * HD + quad * 8;
        float4 x0 = *(const float4*)qp;
        float4 x1 = *(const float4*)(qp + 4);
        float4 y0 = *(const float4*)(qp + 32);
        float4 y1 = *(const float4*)(qp + 36);
        qa0 = pack_bf8(x0, x1, xscale);   // k = 0..31 slice
        qa1 = pack_bf8(y0, y1, xscale);   // k = 32..63 slice
    }

    f4v xa[NTIL];
    if constexpr (PREK) {
        // fragment-ordered prepacked K: fully-coalesced 1KB dwordx4/wave loads
        const s8v* kf = Kbf + ((size_t)bh * (S_LEN / 16) + (wcol0 >> 4)) * 2 * 64 + lane;
        __builtin_amdgcn_s_setprio(1);
#pragma unroll
        for (int t = 0; t < NTIL; ++t) {
            s8v kb0 = kf[(2 * t    ) * 64];
            s8v kb1 = kf[(2 * t + 1) * 64];
            f4v acc = {0.0f, 0.0f, 0.0f, 0.0f};
            acc = __builtin_amdgcn_mfma_f32_16x16x32_bf16(qa0, kb0, acc, 0, 0, 0);
            acc = __builtin_amdgcn_mfma_f32_16x16x32_bf16(qa1, kb1, acc, 0, 0, 0);
            xa[t] = acc;
        }
        __builtin_amdgcn_s_setprio(0);
    } else {
        const float* kbase = Kp + (size_t)bh * S_LEN * HD;
#pragma unroll
        for (int t = 0; t < NTIL; ++t) {
            const float* kp = kbase + ((size_t)(wcol0 + t * 16 + l16)) * HD + quad * 8;
            float4 k0 = *(const float4*)kp;
            float4 k1 = *(const float4*)(kp + 4);
            s8v kb0 = pack_bf8(k0, k1, 1.0f);
            f4v acc = {0.0f, 0.0f, 0.0f, 0.0f};
            acc = __builtin_amdgcn_mfma_f32_16x16x32_bf16(qa0, kb0, acc, 0, 0, 0);
            float4 k2 = *(const float4*)(kp + 32);
            float4 k3 = *(const float4*)(kp + 36);
            s8v kb1 = pack_bf8(k2, k3, 1.0f);
            acc = __builtin_amdgcn_mfma_f32_16x16x32_bf16(qa1, kb1, acc, 0, 0, 0);
            xa[t] = acc;
        }
    }

    // ---- Phase 2: exact row maxes (row = quad*4+g within the Q tile) ----
#pragma unroll
    for (int g = 0; g < 4; ++g) {
        float pm = xa[0][g];
#pragma unroll
        for (int t = 1; t < NTIL; ++t) pm = fmaxf(pm, xa[t][g]);
        pm = dpp_row16_max(pm);
        if (l16 == 15) rmaxw[quad * 4 + g][wv] = pm;
    }
    __syncthreads();
    if (tid < QT) {
        float m = rmaxw[tid][0];
#pragma unroll
        for (int w = 1; w < NW; ++w) m = fmaxf(m, rmaxw[tid][w]);
        rmxf[tid] = m;
    }
    __syncthreads();

    // ---- Phase 3: candidate compaction (single ballot pass) ----
    // Ballots are wave-uniform -> retained in SGPR pairs across counting and
    // scatter (no recompute). Quad totals on the SCALAR pipe. Atomic base
    // broadcast via readlane + cndmask select (no ds_bpermute round-trip).
#pragma unroll
    for (int g = 0; g < 4; ++g) {
        const int   row = quad * 4 + g;
        const float thr = rmxf[row] - 1.0f;
        unsigned long long bm[NTIL];
        unsigned tq0 = 0, tq1 = 0, tq2 = 0, tq3 = 0;   // uniform -> SALU
#pragma unroll
        for (int t = 0; t < NTIL; ++t) {
            bm[t] = __ballot(xa[t][g] > thr);
            tq0 += (unsigned)__popcll(bm[t] & 0x000000000000FFFFull);
            tq1 += (unsigned)__popcll(bm[t] & 0x00000000FFFF0000ull);
            tq2 += (unsigned)__popcll(bm[t] & 0x0000FFFF00000000ull);
            tq3 += (unsigned)__popcll(bm[t] >> 48);
        }
        const int total = (quad & 2) ? ((quad & 1) ? (int)tq3 : (int)tq2)
                                     : ((quad & 1) ? (int)tq1 : (int)tq0);
        int base = 0;
        if (l16 == 0 && total) base = atomicAdd(&ncnt[row], total);
        {   // broadcast lane {0,16,32,48} -> own quad, register-only
            const int b0 = __builtin_amdgcn_readlane(base, 0);
            const int b1 = __builtin_amdgcn_readlane(base, 16);
            const int b2 = __builtin_amdgcn_readlane(base, 32);
            const int b3 = __builtin_amdgcn_readlane(base, 48);
            base = (quad & 2) ? ((quad & 1) ? b3 : b2)
                              : ((quad & 1) ? b1 : b0);
        }
#pragma unroll
        for (int t = 0; t < NTIL; ++t) {
            const float v = xa[t][g];
            const bool pred = (v > thr);
            unsigned gm16 = (unsigned)((bm[t] >> (quad * 16)) & 0xFFFFull);
            if (pred) {
                int pos = base + __popc(gm16 & ((1u << l16) - 1u));
                if (pos < CAP) {
                    candv[row][pos] = v;
                    if constexpr (!DPV) candi[row][pos] = (unsigned short)(wcol0 + t * 16 + l16);
                }
            }
            base += __popc(gm16);
        }
    }
    __syncthreads();

    // ---- Tail phases, specialized on INV2 (block-uniform branch) ----
    auto tail = [&](auto inv2c) {
        constexpr bool INV2 = decltype(inv2c)::value;

        // Phase 4: per-wave tau solve (wave w owns row w; QT == NW)
        {
            const int row = wv;
            const int nc = ncnt[row];
            if (nc <= CAP) {
                if constexpr (!DPV) {   // sparse phase 6 needs padded 8-groups
                    const int ncp = (nc + 7) & ~7;
                    for (int i = nc + lane; i < ncp; i += 64) {
                        candv[row][i] = -3.0e38f;
                        candi[row][i] = 0;
                    }
                }
                const float mx  = rmxf[row];
                const float tl0 = mx - 1.0f;
                const float th  = mx - gp_d;
                float tau, isum;
                if constexpr (INV2) {
                    if (nc <= 256) tau = newton_reg<4>(&candv[row][0], nc, lane, tl0);
                    else           tau = newton_reg<8>(&candv[row][0], nc, lane, tl0);
                    isum = 1.0f;   // converged: |sum(p)-1| <= ~1e-4
                } else {
                    if (nc <= 256) bisect_reg<4, INV2>(&candv[row][0], nc, lane, tl0, th, inv, tau, isum);
                    else           bisect_reg<8, INV2>(&candv[row][0], nc, lane, tl0, th, inv, tau, isum);
                }
                if (lane == 0) { taus[row] = tau; isums[row] = isum; }
            }
        }

        // Phase 4b: block-wide fallback for overflow rows (nc > CAP; rare)
#pragma unroll 1
        for (int r = 0; r < QT; ++r) {
            if (ncnt[r] > CAP) {   // uniform condition -> barriers are safe
                const float mx = rmxf[r];
                const int g = r & 3;
                const bool mine = (quad == (r >> 2));
                float tau = mx - 1.0f;
                float s0 = 0.0f;
                if (mine) {
#pragma unroll
                    for (int t = 0; t < NTIL; ++t) s0 += pfun_t<INV2>(xa[t][g] - tau, inv);
                }
                s0 = wave_sum(s0);
                if (lane == 0) redw[wv] = s0;
                __syncthreads();
                float f_lo = -1.0f;
                for (int w = 0; w < NW; ++w) f_lo += redw[w];
                __syncthreads();
                float dm = (mx - gp_d) - tau;
                for (int it = 0; it < NITER; ++it) {
                    dm *= 0.5f;
                    float tm = tau + dm;
                    float s = 0.0f;
                    if (mine) {
#pragma unroll
                        for (int t = 0; t < NTIL; ++t) s += pfun_t<INV2>(xa[t][g] - tm, inv);
                    }
                    s = wave_sum(s);
                    if (lane == 0) redw[wv] = s;
                    __syncthreads();
                    float fm = -1.0f;
                    for (int w = 0; w < NW; ++w) fm += redw[w];
                    __syncthreads();
                    if (fm * f_lo >= 0.0f) tau = tm;
                }
                float s = 0.0f;
                if (mine) {
#pragma unroll
                    for (int t = 0; t < NTIL; ++t) s += pfun_t<INV2>(xa[t][g] - tau, inv);
                }
                s = wave_sum(s);
                if (lane == 0) redw[wv] = s;
                __syncthreads();
                float ssum = 0.0f;
                for (int w = 0; w < NW; ++w) ssum += redw[w];
                __syncthreads();
                if (tid == 0) { taus[r] = tau; isums[r] = 1.0f / ssum; }
            }
        }
        __syncthreads();   // taus/isums visible; candv reads complete (smem reuse OK)

        if constexpr (DPV) {
            // ---- Phase 5+6 (dense PV): write p_attn (non-temporal); stage
            // bf16 p (PERMUTED k-order: position p = l16*8 + t <-> col
            // t*16 + l16, so a lane's 8 row-values are one contiguous 16B
            // chunk) via ds_write_b128 with XOR chunk swizzle; MFMA against
            // identically-permuted V.
            unsigned short* pwf = (unsigned short*)smem + wv * 2048;  // 4KB/wave: [16 rows][128]
            const size_t prow_base = ((size_t)bh * S_LEN + q0) * S_LEN;
#pragma unroll
            for (int g = 0; g < 4; ++g) {
                const int row = quad * 4 + g;
                const float tau  = taus[row];
                const float isum = isums[row];
                float* prow = pattn + prow_base + (size_t)row * S_LEN + wcol0 + l16;
                union { s8v s; unsigned u[4]; } pk;
                float pprev = 0.0f;
#pragma unroll
                for (int t = 0; t < NTIL; ++t) {
                    float p2 = pfun_t<INV2>(xa[t][g] - tau, inv);
                    __builtin_nontemporal_store(p2 * isum, &prow[t * 16]);  // normalized p_attn
                    if (t & 1) pk.u[t >> 1] = f2bf2(pprev, p2);
                    else       pprev = p2;
                }
                const int c = (l16 ^ row) & 15;               // XOR chunk swizzle
                *(s8v*)&pwf[row * 128 + c * 8] = pk.s;        // one b128 store
            }
            // A-frags (wave-local; DS in-order): row = l16, chunk c = kt*4+quad
            s8v afrag[4];
#pragma unroll
            for (int kt = 0; kt < 4; ++kt) {
                const int c = ((kt * 4 + quad) ^ l16) & 15;
                afrag[kt] = *(const s8v*)&pwf[l16 * 128 + c * 8];
            }
            // B-frags from permuted prepacked V; 16 MFMA: out_part[16 rows][64 d]
            const s8v* vf = Vbf + ((size_t)bh * (S_LEN / 32) + (wcol0 >> 5)) * 4 * 64 + lane;
            f4v oacc[4];
#pragma unroll
            for (int dt = 0; dt < 4; ++dt) oacc[dt] = (f4v){0.0f, 0.0f, 0.0f, 0.0f};
            __builtin_amdgcn_s_setprio(1);
#pragma unroll
            for (int kt = 0; kt < 4; ++kt) {
#pragma unroll
                for (int dt = 0; dt < 4; ++dt) {
                    s8v b = vf[(kt * 4 + dt) * 64];
                    oacc[dt] = __builtin_amdgcn_mfma_f32_16x16x32_bf16(afrag[kt], b, oacc[dt], 0, 0, 0);
                }
            }
            __builtin_amdgcn_s_setprio(0);
            // Wave-private partial store ALIASED onto this wave's pw region
            // (DS ops are in-order per wave: afrag reads precede these writes;
            // no other wave touches this 4KB). Layout [16 rows][64 d] f32 with
            // quad-XOR on d: store 2-way bank (free), reduce read conflict-free.
            float* pr = (float*)pwf;
#pragma unroll
            for (int dt = 0; dt < 4; ++dt) {
#pragma unroll
                for (int g = 0; g < 4; ++g) {
                    pr[(quad * 4 + g) * 64 + ((dt * 16 + l16) ^ (quad << 4))] = oacc[dt][g];
                }
            }
            __syncthreads();   // single epilogue barrier: all partials visible
            // reduce 16 wave-partials: thread (wv,lane) owns (row=wv, d=lane);
            // element (r,d) of wave w lives at w*1024 + r*64 + (d ^ ((r>>2)<<4))
            const int rd = lane ^ ((wv >> 2) << 4);
            float s = 0.0f;
#pragma unroll
            for (int w = 0; w < NW; ++w) s += ((float*)smem)[w * 1024 + wv * 64 + rd];
            __builtin_nontemporal_store(s * isums[wv],
                &outp[((size_t)bh * S_LEN + q0 + wv) * HD + lane]);
        } else {
            // ---- Phase 5: write normalized p_attn ----
            const size_t prow_base = ((size_t)bh * S_LEN + q0) * S_LEN;
#pragma unroll
            for (int g = 0; g < 4; ++g) {
                const int row = quad * 4 + g;
                const float tau  = taus[row];
                const float isum = isums[row];
                float* prow = pattn + prow_base + (size_t)row * S_LEN + wcol0 + l16;
#pragma unroll
                for (int t = 0; t < NTIL; ++t) {
                    prow[t * 16] = pfun_t<INV2>(xa[t][g] - tau, inv) * isum;
                }
            }
            __threadfence_block();
            __syncthreads();

            // ---- Phase 6: out = p @ V, sparse over candidates (lane == d) ----
            const int row  = wv;
            const int qrow = q0 + row;
            const int nc   = ncnt[row];
            const float tau  = taus[row];
            const float isum = isums[row];
            float oacc = 0.0f;
            if (nc <= CAP) {
                const int ncp = (nc + 7) & ~7;
                for (int i = lane; i < ncp; i += 64)  // candv := unnormalized p
                    candv[row][i] = pfun_t<INV2>(candv[row][i] - tau, inv);
                float oacc1 = 0.0f;
                for (int i = 0; i < ncp; i += 8) {
#pragma unroll
                    for (int u = 0; u < 8; u += 2) {  // dual acc: halve fmaf chain
                        oacc  = fmaf(candv[row][i + u],
                                     vbase[(size_t)candi[row][i + u] * HD + lane], oacc);
                        oacc1 = fmaf(candv[row][i + u + 1],
                                     vbase[(size_t)candi[row][i + u + 1] * HD + lane], oacc1);
                    }
                }
                oacc = (oacc + oacc1) * isum;
            } else {
                const float* prow = pattn + ((size_t)bh * S_LEN + qrow) * S_LEN;
                for (int k = 0; k < S_LEN; ++k)
                    oacc = fmaf(prow[k], vbase[(size_t)k * HD + lane], oacc);
            }
            outp[((size_t)bh * S_LEN + qrow) * HD + lane] = oacc;
        }
    };

    if (inv2) tail(BoolT<true>{});   // alpha == 1.5 fast path (u*u)
    else      tail(BoolT<false>{});  // generic alpha (powf)
}

extern "C" void kernel_launch(void* const* d_in, const int* in_sizes, int n_in,
                              void* d_out, int out_size, void* d_ws, size_t ws_size,
                              hipStream_t stream) {
    const float* Q = (const float*)d_in[0];
    const float* K = (const float*)d_in[1];
    const float* V = (const float*)d_in[2];
    const float* A = (const float*)d_in[3];
    float* out = (float*)d_out;
    const int BH = in_sizes[0] / (S_LEN * HD);          // 64
    float* p = out + (size_t)BH * S_LEN * HD;           // p_attn follows out
    dim3 grid(S_LEN / QT, BH);

    const size_t kb_bytes = (size_t)BH * S_LEN * HD * sizeof(short);  // 16.8 MB
    const int nK = BH * (S_LEN / 16) * 2 * 64;          // K 16B frag chunks
    const int nV = BH * (S_LEN / 32) * 4 * 64;          // V 16B frag chunks

    if (d_ws != nullptr && ws_size >= 2 * kb_bytes) {
        s8v* Kb = (s8v*)d_ws;
        s8v* Vb = (s8v*)((char*)d_ws + kb_bytes);
        pack_kv<<<dim3((nK + nV) / 256), 256, 0, stream>>>(K, V, Kb, Vb, nK);
        entmax_attn<true, true><<<grid, NT, 0, stream>>>(Q, K, V, A, out, p, Kb, Vb);
    } else if (d_ws != nullptr && ws_size >= kb_bytes) {
        s8v* Kb = (s8v*)d_ws;
        pack_kv<<<dim3(nK / 256), 256, 0, stream>>>(K, V, Kb, nullptr, nK);
        entmax_attn<true, false><<<grid, NT, 0, stream>>>(Q, K, V, A, out, p, Kb, nullptr);
    } else {
        entmax_attn<false, false><<<grid, NT, 0, stream>>>(Q, K, V, A, out, p, nullptr, nullptr);
    }
}